// Round 15
// baseline (238.351 us; speedup 1.0000x reference)
//
#include <hip/hip_runtime.h>
#include <hip/hip_bf16.h>
#include <stdint.h>

// GCN layer: out = D^-1/2 (A+I) D^-1/2 (x W + b)
// N=100000 nodes, E=3.2M edges, 256 -> 128 features.
// Pipeline (4 launches): LDS-staged partition into fixed-capacity buckets
// (512 rows, 20480 cap; int4 NT loads; W-cast folded in; relative gcur) ->
// per-bucket CSR build (1024 thr, uint4 NT loads; emits deg -> dis, offs,
// cnts) -> bf16 MFMA GEMM (512 thr / M-tile 128, NT x-loads, stores
// hu'=bf16(dis*h)) -> wave-per-node gather, scalar addressing, 8 gathers in
// flight (measured at the beyond-L2 random-fetch ceiling ~4 TB/s).

#define RB     512     // rows per bucket
#define RBSH   9
#define NBMAX  256     // >= NB = ceil(100000/512) = 196
#define CHUNK  12288   // edges per partition block (LDS sorted array = 48 KB)
#define BSTRIDE 20480  // fixed bucket capacity (exp 16327, sigma 127 -> +32s)

typedef __attribute__((ext_vector_type(8))) short short8v;   // 8 bf16
typedef __attribute__((ext_vector_type(16))) float f32x16;
typedef __attribute__((ext_vector_type(4))) int int4v;
typedef __attribute__((ext_vector_type(4))) unsigned int uint4v;
typedef __attribute__((ext_vector_type(4))) float float4v;

__device__ __forceinline__ float bf_lo(uint32_t p) { return __uint_as_float(p << 16); }
__device__ __forceinline__ float bf_hi(uint32_t p) { return __uint_as_float(p & 0xffff0000u); }

__device__ __forceinline__ uint32_t f2bf(float f) {
  uint32_t u = __float_as_uint(f);
  return (u + 0x7fffu + ((u >> 16) & 1u)) >> 16;  // RNE
}

// HW pack-convert: (lo, hi) -> (bf16(hi)<<16)|bf16(lo), RNE via v_cvt_pk_bf16_f32
__device__ __forceinline__ uint32_t cvt_pk(float lo, float hi) {
  __hip_bfloat162 b = __float22bfloat162_rn(float2{lo, hi});
  union { __hip_bfloat162 b; uint32_t u; } cv;
  cv.b = b;
  return cv.u;
}

// ---- W cast (fallback path only; main path folds it into k_part) ----
__global__ void k_wcast(const float* __restrict__ W, uint16_t* __restrict__ wbf) {
  int t = blockIdx.x * 256 + threadIdx.x;   // 32768 total
  int col = t >> 8, k = t & 255;
  wbf[t] = (uint16_t)f2bf(W[k * 128 + col]);
}

// ---- LDS-staged partition (int4 NT loads); W-cast folded in; gcur relative ----
__launch_bounds__(1024)
__global__ void k_part(const int* __restrict__ rows, const int* __restrict__ cols,
                       int E, int NB, int* __restrict__ gcur,
                       uint32_t* __restrict__ temp,
                       const float* __restrict__ W, uint16_t* __restrict__ wbf) {
  __shared__ uint32_t sorted[CHUNK];  // 48 KB
  __shared__ int hist[NBMAX];
  __shared__ int scanv[NBMAX];
  __shared__ int res[NBMAX];
  int tid = threadIdx.x;
  int base = blockIdx.x * CHUNK;
  int cnt = min(CHUNK, E - base);    // E,CHUNK multiples of 4 -> cnt % 4 == 0

  {  // folded W cast: 32768 elements over the first 32 blocks
    int t = blockIdx.x * 1024 + tid;
    if (t < 32768) {
      int col = t >> 8, k = t & 255;
      wbf[t] = (uint16_t)f2bf(W[k * 128 + col]);
    }
  }
  for (int i = tid; i < NBMAX; i += 1024) hist[i] = 0;
  __syncthreads();
  for (int i = tid * 4; i < cnt; i += 4096) {
    int4v r4 = __builtin_nontemporal_load((const int4v*)&rows[base + i]);
    atomicAdd(&hist[r4.x >> RBSH], 1);
    atomicAdd(&hist[r4.y >> RBSH], 1);
    atomicAdd(&hist[r4.z >> RBSH], 1);
    atomicAdd(&hist[r4.w >> RBSH], 1);
  }
  __syncthreads();
  if (tid < NBMAX) scanv[tid] = hist[tid];
  __syncthreads();
  for (int d = 1; d < NBMAX; d <<= 1) {
    int v = 0;
    if (tid < NBMAX && tid >= d) v = scanv[tid - d];
    __syncthreads();
    if (tid < NBMAX) scanv[tid] += v;
    __syncthreads();
  }
  if (tid < NB) {
    int c = hist[tid];
    // gcur is RELATIVE (memset-0 init); absolute base = tid*BSTRIDE + cursor
    res[tid] = (c ? atomicAdd(&gcur[tid], c) : 0) + tid * BSTRIDE;
    hist[tid] = scanv[tid] - c;                   // lbase -> cursor
  }
  __syncthreads();
  for (int i = tid * 4; i < cnt; i += 4096) {
    int4v r4 = __builtin_nontemporal_load((const int4v*)&rows[base + i]);
    int4v c4 = __builtin_nontemporal_load((const int4v*)&cols[base + i]);
    int p0 = atomicAdd(&hist[r4.x >> RBSH], 1);
    sorted[p0] = ((uint32_t)(r4.x & (RB - 1)) << 17) | (uint32_t)c4.x;
    int p1 = atomicAdd(&hist[r4.y >> RBSH], 1);
    sorted[p1] = ((uint32_t)(r4.y & (RB - 1)) << 17) | (uint32_t)c4.y;
    int p2 = atomicAdd(&hist[r4.z >> RBSH], 1);
    sorted[p2] = ((uint32_t)(r4.z & (RB - 1)) << 17) | (uint32_t)c4.z;
    int p3 = atomicAdd(&hist[r4.w >> RBSH], 1);
    sorted[p3] = ((uint32_t)(r4.w & (RB - 1)) << 17) | (uint32_t)c4.w;
  }
  __syncthreads();
  int wv = tid >> 6, lane = tid & 63;
  for (int b = wv; b < NB; b += 16) {   // wave-cooperative contiguous run copy
    int st = b ? scanv[b - 1] : 0;
    int en = scanv[b];
    int gb = res[b];
    for (int j = st + lane; j < en; j += 64)
      temp[gb + (j - st)] = sorted[j];
  }
}

// ---- per-bucket CSR build (1024 thr, uint4 NT); emits deg -> dis, offs, cnts ----
__launch_bounds__(1024)
__global__ void k_csr_build(const int* __restrict__ gcur,
                            const uint32_t* __restrict__ temp, int N,
                            int* __restrict__ offs, int* __restrict__ cnts,
                            float* __restrict__ dis, int* __restrict__ csr) {
  __shared__ int cnt[RB];   // per-node count -> cursor
  __shared__ int S[256];
  int b = blockIdx.x;
  int tid = threadIdx.x;
  int base = b * BSTRIDE;   // 16B-aligned (BSTRIDE % 4 == 0)
  int cb = gcur[b];         // relative cursor == bucket count
  int cb4 = cb & ~3;

  if (tid < RB) cnt[tid] = 0;
  __syncthreads();
  for (int i = tid * 4; i < cb4; i += 4096) {
    uint4v t4 = __builtin_nontemporal_load((const uint4v*)&temp[base + i]);
    atomicAdd(&cnt[t4.x >> 17], 1);
    atomicAdd(&cnt[t4.y >> 17], 1);
    atomicAdd(&cnt[t4.z >> 17], 1);
    atomicAdd(&cnt[t4.w >> 17], 1);
  }
  if (tid < cb - cb4)                     // tail 0..3
    atomicAdd(&cnt[temp[base + cb4 + tid] >> 17], 1);
  __syncthreads();
  int a0 = 0, a1 = 0, ex0 = 0;
  if (tid < 256) {
    a0 = cnt[2 * tid]; a1 = cnt[2 * tid + 1];
    S[tid] = a0 + a1;
  }
  __syncthreads();
  for (int d = 1; d < 256; d <<= 1) {
    int v = 0;
    if (tid < 256 && tid >= d) v = S[tid - d];
    __syncthreads();
    if (tid < 256) S[tid] += v;
    __syncthreads();
  }
  if (tid < 256) {
    ex0 = S[tid] - (a0 + a1);
    int r0 = b * RB + 2 * tid;
    if (r0 < N) {
      dis[r0] = rsqrtf((float)(a0 + 1));
      offs[r0] = base + ex0;
      cnts[r0] = a0;
    }
    if (r0 + 1 < N) {
      dis[r0 + 1] = rsqrtf((float)(a1 + 1));
      offs[r0 + 1] = base + ex0 + a0;
      cnts[r0 + 1] = a1;
    }
  }
  __syncthreads();
  if (tid < 256) {
    cnt[2 * tid]     = ex0;       // cursor start
    cnt[2 * tid + 1] = ex0 + a0;
  }
  __syncthreads();
  for (int i = tid * 4; i < cb4; i += 4096) {
    uint4v t4 = __builtin_nontemporal_load((const uint4v*)&temp[base + i]);
    int p0 = atomicAdd(&cnt[t4.x >> 17], 1);
    csr[base + p0] = (int)(t4.x & 0x1FFFF);
    int p1 = atomicAdd(&cnt[t4.y >> 17], 1);
    csr[base + p1] = (int)(t4.y & 0x1FFFF);
    int p2 = atomicAdd(&cnt[t4.z >> 17], 1);
    csr[base + p2] = (int)(t4.z & 0x1FFFF);
    int p3 = atomicAdd(&cnt[t4.w >> 17], 1);
    csr[base + p3] = (int)(t4.w & 0x1FFFF);
  }
  if (tid < cb - cb4) {
    uint32_t pk = temp[base + cb4 + tid];
    int p = atomicAdd(&cnt[pk >> 17], 1);
    csr[base + p] = (int)(pk & 0x1FFFF);
  }
}

// ---- bf16 MFMA GEMM: h = x W + b; store hu[m*64+j] = bf16(dis[m]*h) pair ----
// Block: 512 thr = 8 waves, M-tile 128, all 128 cols -> 64 KB W-LDS amortized
// at 16 waves/CU (4/SIMD). Wave w: rows [32(w&3),+32), cols [64(w>>2),+64) as
// two 32x32 tiles. A-frags NT-loaded from global (x rows used once, v_cvt_pk);
// W in LDS bf16 [col][k], 16B-slot XOR swizzle => conflict-free b128.
// hu dword j packs feats (p, p+32), p = (j&31) | ((j&32)<<1).
__launch_bounds__(512)
__global__ void k_gemm(const float* __restrict__ x, const uint16_t* __restrict__ wbf,
                       const float* __restrict__ bias, const float* __restrict__ dis,
                       uint32_t* __restrict__ hu, int M) {
  __shared__ uint16_t wlds[32768];  // 64 KB
  int tid = threadIdx.x;
  {
    const uint4* src = (const uint4*)wbf;
#pragma unroll
    for (int i = 0; i < 8; ++i) {      // 8 * 512 = 4096 chunks = full 64 KB
      int chunk = i * 512 + tid;       // 16B chunks: col = chunk>>5, slot = chunk&31
      uint4 v = src[chunk];
      int col = chunk >> 5, s = chunk & 31;
      int sp = s ^ (col & 31);
      *(uint4*)&wlds[col * 256 + sp * 8] = v;
    }
  }
  int w = tid >> 6, l = tid & 63;
  int lr = l & 31, g = l >> 5;
  int row = blockIdx.x * 128 + (w & 3) * 32 + lr;
  int c0 = (w >> 2) * 64;
  bool valid = row < M;
  const float* xrow = x + (size_t)row * 256;
  f32x16 acc0 = {}, acc1 = {};
  __syncthreads();
#pragma unroll
  for (int kt = 0; kt < 16; ++kt) {
    int k0 = kt * 16 + g * 8;          // lane's 8 contiguous k
    float4v f0 = {0.f, 0.f, 0.f, 0.f}, f1 = {0.f, 0.f, 0.f, 0.f};
    if (valid) {
      f0 = __builtin_nontemporal_load((const float4v*)(xrow + k0));
      f1 = __builtin_nontemporal_load((const float4v*)(xrow + k0 + 4));
    }
    union { uint32_t u[4]; short8v v; } av;
    av.u[0] = cvt_pk(f0.x, f0.y);
    av.u[1] = cvt_pk(f0.z, f0.w);
    av.u[2] = cvt_pk(f1.x, f1.y);
    av.u[3] = cvt_pk(f1.z, f1.w);
    int sp = (kt * 2 + g) ^ lr;        // swizzled 16B slot
    short8v b0 = *(short8v*)&wlds[(c0 + lr) * 256 + sp * 8];
    short8v b1 = *(short8v*)&wlds[(c0 + 32 + lr) * 256 + sp * 8];
    acc0 = __builtin_amdgcn_mfma_f32_32x32x16_bf16(av.v, b0, acc0, 0, 0, 0);
    acc1 = __builtin_amdgcn_mfma_f32_32x32x16_bf16(av.v, b1, acc1, 0, 0, 0);
  }
  int j = lr + (w >> 2) * 32;          // hu pair index
  int p = c0 + lr;                     // actual feature col of tile0
  float bl = bias[p], bh = bias[p + 32];
#pragma unroll
  for (int r = 0; r < 16; ++r) {
    int mrow = blockIdx.x * 128 + (w & 3) * 32 + (r & 3) + 8 * (r >> 2) + 4 * g;
    if (mrow < M) {
      float di = dis[mrow];
      hu[(size_t)mrow * 64 + j] = cvt_pk(di * (acc0[r] + bl), di * (acc1[r] + bh));
    }
  }
}

// ---- aggregation: wave per node, scalar addressing, 8 gathers in flight ----
// offs/cnts readfirstlane'd -> csr reads on the scalar pipe, hu row base SGPR
// + loop-invariant lane offset. Measured at the beyond-L2 random-fetch ceiling.
__launch_bounds__(256)
__global__ void k_aggregate(const uint32_t* __restrict__ hu, const float* __restrict__ dis,
                            const int* __restrict__ offs, const int* __restrict__ cnts,
                            const int* __restrict__ csr,
                            float* __restrict__ out, int N) {
  int wid = blockIdx.x * 4 + (threadIdx.x >> 6);
  int lane = threadIdx.x & 63;
  if (wid >= N) return;
  int e0  = __builtin_amdgcn_readfirstlane(offs[wid]);
  int cnt = __builtin_amdgcn_readfirstlane(cnts[wid]);
  const int* cp = csr + e0;                       // uniform (SGPR) base
  const uint32_t* hrow = hu + ((size_t)(uint32_t)wid << 6);
  uint32_t ps = hrow[lane];
  float ax = bf_lo(ps);   // self loop: hu' already has dis folded in
  float ay = bf_hi(ps);
  int i = 0;
  for (; i + 8 <= cnt; i += 8) {                  // 8 independent gathers in flight
    int c0 = cp[i],     c1 = cp[i + 1], c2 = cp[i + 2], c3 = cp[i + 3];
    int c4 = cp[i + 4], c5 = cp[i + 5], c6 = cp[i + 6], c7 = cp[i + 7];
    uint32_t p0 = hu[((size_t)(uint32_t)c0 << 6) + lane];
    uint32_t p1 = hu[((size_t)(uint32_t)c1 << 6) + lane];
    uint32_t p2 = hu[((size_t)(uint32_t)c2 << 6) + lane];
    uint32_t p3 = hu[((size_t)(uint32_t)c3 << 6) + lane];
    uint32_t p4 = hu[((size_t)(uint32_t)c4 << 6) + lane];
    uint32_t p5 = hu[((size_t)(uint32_t)c5 << 6) + lane];
    uint32_t p6 = hu[((size_t)(uint32_t)c6 << 6) + lane];
    uint32_t p7 = hu[((size_t)(uint32_t)c7 << 6) + lane];
    ax += bf_lo(p0) + bf_lo(p1) + bf_lo(p2) + bf_lo(p3)
        + bf_lo(p4) + bf_lo(p5) + bf_lo(p6) + bf_lo(p7);
    ay += bf_hi(p0) + bf_hi(p1) + bf_hi(p2) + bf_hi(p3)
        + bf_hi(p4) + bf_hi(p5) + bf_hi(p6) + bf_hi(p7);
  }
  for (; i + 4 <= cnt; i += 4) {
    int c0 = cp[i], c1 = cp[i + 1], c2 = cp[i + 2], c3 = cp[i + 3];
    uint32_t p0 = hu[((size_t)(uint32_t)c0 << 6) + lane];
    uint32_t p1 = hu[((size_t)(uint32_t)c1 << 6) + lane];
    uint32_t p2 = hu[((size_t)(uint32_t)c2 << 6) + lane];
    uint32_t p3 = hu[((size_t)(uint32_t)c3 << 6) + lane];
    ax += bf_lo(p0) + bf_lo(p1) + bf_lo(p2) + bf_lo(p3);
    ay += bf_hi(p0) + bf_hi(p1) + bf_hi(p2) + bf_hi(p3);
  }
  for (; i < cnt; ++i) {
    int c = cp[i];
    uint32_t p = hu[((size_t)(uint32_t)c << 6) + lane];
    ax += bf_lo(p);
    ay += bf_hi(p);
  }
  float di = dis[wid];
  int p = (lane & 31) | ((lane & 32) << 1);
  float* orow = out + (size_t)wid * 128;
  __builtin_nontemporal_store(di * ax, &orow[p]);
  __builtin_nontemporal_store(di * ay, &orow[p + 32]);
}

// ---- fallback path (small workspace): count -> dis -> per-edge atomics ----
__global__ void k_count(const int* __restrict__ rows, int E, int* __restrict__ deg) {
  int e = blockIdx.x * blockDim.x + threadIdx.x;
  if (e < E) atomicAdd(&deg[rows[e]], 1);
}

__global__ void k_dis(const int* __restrict__ deg, float* __restrict__ dis, int N) {
  int i = blockIdx.x * blockDim.x + threadIdx.x;
  if (i < N) dis[i] = rsqrtf((float)(deg[i] + 1));
}

__launch_bounds__(256)
__global__ void k_selfinit(const uint32_t* __restrict__ hu, const float* __restrict__ dis,
                           float* __restrict__ out, int N) {
  int wid = blockIdx.x * 4 + (threadIdx.x >> 6);
  int lane = threadIdx.x & 63;
  if (wid >= N) return;
  float di = dis[wid];
  uint32_t p = hu[(size_t)wid * 64 + lane];
  int pc = (lane & 31) | ((lane & 32) << 1);
  out[(size_t)wid * 128 + pc] = di * bf_lo(p);
  out[(size_t)wid * 128 + pc + 32] = di * bf_hi(p);
}

__launch_bounds__(256)
__global__ void k_edge_atomic(const int* __restrict__ rows, const int* __restrict__ cols, int E,
                              const uint32_t* __restrict__ hu, const float* __restrict__ dis,
                              float* __restrict__ out) {
  int wid = blockIdx.x * 4 + (threadIdx.x >> 6);
  int lane = threadIdx.x & 63;
  if (wid >= E) return;
  int r = rows[wid], c = cols[wid];
  float w = dis[r];  // hu'[c] already carries dis[c]
  uint32_t p = hu[(size_t)c * 64 + lane];
  int pc = (lane & 31) | ((lane & 32) << 1);
  atomicAdd(&out[(size_t)r * 128 + pc], w * bf_lo(p));
  atomicAdd(&out[(size_t)r * 128 + pc + 32], w * bf_hi(p));
}

extern "C" void kernel_launch(void* const* d_in, const int* in_sizes, int n_in,
                              void* d_out, int out_size, void* d_ws, size_t ws_size,
                              hipStream_t stream) {
  const float* x    = (const float*)d_in[0];
  const int*   ei   = (const int*)d_in[1];
  const float* W    = (const float*)d_in[2];
  const float* bias = (const float*)d_in[3];
  float* out = (float*)d_out;

  const int N = in_sizes[0] / 256;   // 100000
  const int E = in_sizes[1] / 2;     // 3200000
  const int NB = (N + RB - 1) / RB;  // 196 buckets of 512 rows
  const int* rows = ei;
  const int* cols = ei + E;

  // workspace layout (256B aligned slices)
  size_t off = 0;
  auto alloc = [&](size_t bytes) -> void* {
    void* p = (char*)d_ws + off;
    off += (bytes + 255) & ~(size_t)255;
    return p;
  };
  uint32_t* hu    = (uint32_t*)alloc((size_t)N * 64 * 4);  // bf16-packed dis*h
  float*    dis   = (float*)alloc((size_t)N * 4);
  int*      deg   = (int*)alloc((size_t)N * 4);            // fallback only
  uint16_t* wbf   = (uint16_t*)alloc(32768 * 2);           // bf16 W, [col][k]
  int*      gcur  = (int*)alloc((size_t)NBMAX * 4);
  int*      offs  = (int*)alloc((size_t)N * 4);
  int*      cnts  = (int*)alloc((size_t)N * 4);
  size_t small_end = off;
  uint32_t* temp  = (uint32_t*)alloc((size_t)NB * BSTRIDE * 4);
  int*      csr   = (int*)alloc((size_t)NB * BSTRIDE * 4);
  bool full = (off <= ws_size);
  bool atomic_ok = (small_end <= ws_size);

  if (full) {
    hipMemsetAsync(gcur, 0, (size_t)NBMAX * 4, stream);   // relative cursors
    k_part<<<(E + CHUNK - 1) / CHUNK, 1024, 0, stream>>>(rows, cols, E, NB, gcur,
                                                         temp, W, wbf);
    k_csr_build<<<NB, 1024, 0, stream>>>(gcur, temp, N, offs, cnts, dis, csr);
    k_gemm<<<(N + 127) / 128, 512, 0, stream>>>(x, wbf, bias, dis, hu, N);
    k_aggregate<<<(N + 3) / 4, 256, 0, stream>>>(hu, dis, offs, cnts, csr, out, N);
  } else if (atomic_ok) {
    k_wcast<<<128, 256, 0, stream>>>(W, wbf);
    hipMemsetAsync(deg, 0, (size_t)N * 4, stream);
    k_count<<<(E + 255) / 256, 256, 0, stream>>>(rows, E, deg);
    k_dis<<<(N + 255) / 256, 256, 0, stream>>>(deg, dis, N);
    k_gemm<<<(N + 127) / 128, 512, 0, stream>>>(x, wbf, bias, dis, hu, N);
    k_selfinit<<<(N + 3) / 4, 256, 0, stream>>>(hu, dis, out, N);
    k_edge_atomic<<<(E + 3) / 4, 256, 0, stream>>>(rows, cols, E, hu, dis, out);
  }
}

// Round 16
// 195.490 us; speedup vs baseline: 1.2192x; 1.2192x over previous
//
#include <hip/hip_runtime.h>
#include <hip/hip_bf16.h>
#include <stdint.h>

// GCN layer: out = D^-1/2 (A+I) D^-1/2 (x W + b)
// N=100000 nodes, E=3.2M edges, 256 -> 128 features.
// Pipeline: W pre-cast to bf16 [col][k] (+ gcur init) -> LDS-staged partition
// into FIXED-CAPACITY buckets (512 rows, 20480 cap; int4-vectorized) ->
// per-bucket CSR build (1024 thr, uint4-vectorized; emits deg -> dis, offs,
// cnts) -> bf16 MFMA GEMM (512 thr / M-tile 128, stores hu'=bf16(dis*h)) ->
// wave-per-node gather, scalar addressing, 8 gathers in flight
// (measured at the beyond-L2 random-fetch ceiling ~4 TB/s).
// NOTE: no nontemporal loads anywhere — x is reused across col-tile wave
// groups, rows/temp are read twice per kernel (round-15 regression lesson).

#define RB     512     // rows per bucket
#define RBSH   9
#define NBMAX  256     // >= NB = ceil(100000/512) = 196
#define CHUNK  12288   // edges per partition block (LDS sorted array = 48 KB)
#define BSTRIDE 20480  // fixed bucket capacity (exp 16327, sigma 127 -> +32s)

typedef __attribute__((ext_vector_type(8))) short short8v;   // 8 bf16
typedef __attribute__((ext_vector_type(16))) float f32x16;

__device__ __forceinline__ float bf_lo(uint32_t p) { return __uint_as_float(p << 16); }
__device__ __forceinline__ float bf_hi(uint32_t p) { return __uint_as_float(p & 0xffff0000u); }

__device__ __forceinline__ uint32_t f2bf(float f) {
  uint32_t u = __float_as_uint(f);
  return (u + 0x7fffu + ((u >> 16) & 1u)) >> 16;  // RNE
}

// HW pack-convert: (lo, hi) -> (bf16(hi)<<16)|bf16(lo), RNE via v_cvt_pk_bf16_f32
__device__ __forceinline__ uint32_t cvt_pk(float lo, float hi) {
  __hip_bfloat162 b = __float22bfloat162_rn(float2{lo, hi});
  union { __hip_bfloat162 b; uint32_t u; } cv;
  cv.b = b;
  return cv.u;
}

// ---- W cast: wbf[col*256 + k] = bf16(W[k*128 + col]); block 0 inits gcur ----
__global__ void k_wcast(const float* __restrict__ W, uint16_t* __restrict__ wbf,
                        int* __restrict__ gcur, int NB) {
  int tid = threadIdx.x;
  if (blockIdx.x == 0 && tid < NB) gcur[tid] = tid * BSTRIDE;
  int t = blockIdx.x * 256 + tid;   // 32768 total
  int col = t >> 8, k = t & 255;
  wbf[t] = (uint16_t)f2bf(W[k * 128 + col]);
}

// ---- LDS-staged partition (int4-vectorized): chunk -> bucket runs -> burst out
__launch_bounds__(1024)
__global__ void k_part(const int* __restrict__ rows, const int* __restrict__ cols,
                       int E, int NB, int* __restrict__ gcur,
                       uint32_t* __restrict__ temp) {
  __shared__ uint32_t sorted[CHUNK];  // 48 KB
  __shared__ int hist[NBMAX];
  __shared__ int scanv[NBMAX];
  __shared__ int res[NBMAX];
  int tid = threadIdx.x;
  int base = blockIdx.x * CHUNK;
  int cnt = min(CHUNK, E - base);    // E,CHUNK multiples of 4 -> cnt % 4 == 0

  for (int i = tid; i < NBMAX; i += 1024) hist[i] = 0;
  __syncthreads();
  for (int i = tid * 4; i < cnt; i += 4096) {
    int4 r4 = *(const int4*)&rows[base + i];
    atomicAdd(&hist[r4.x >> RBSH], 1);
    atomicAdd(&hist[r4.y >> RBSH], 1);
    atomicAdd(&hist[r4.z >> RBSH], 1);
    atomicAdd(&hist[r4.w >> RBSH], 1);
  }
  __syncthreads();
  if (tid < NBMAX) scanv[tid] = hist[tid];
  __syncthreads();
  for (int d = 1; d < NBMAX; d <<= 1) {
    int v = 0;
    if (tid < NBMAX && tid >= d) v = scanv[tid - d];
    __syncthreads();
    if (tid < NBMAX) scanv[tid] += v;
    __syncthreads();
  }
  if (tid < NB) {
    int c = hist[tid];
    res[tid] = c ? atomicAdd(&gcur[tid], c) : 0;  // one reservation per bucket
    hist[tid] = scanv[tid] - c;                   // lbase -> cursor
  }
  __syncthreads();
  for (int i = tid * 4; i < cnt; i += 4096) {
    int4 r4 = *(const int4*)&rows[base + i];
    int4 c4 = *(const int4*)&cols[base + i];
    int p0 = atomicAdd(&hist[r4.x >> RBSH], 1);
    sorted[p0] = ((uint32_t)(r4.x & (RB - 1)) << 17) | (uint32_t)c4.x;
    int p1 = atomicAdd(&hist[r4.y >> RBSH], 1);
    sorted[p1] = ((uint32_t)(r4.y & (RB - 1)) << 17) | (uint32_t)c4.y;
    int p2 = atomicAdd(&hist[r4.z >> RBSH], 1);
    sorted[p2] = ((uint32_t)(r4.z & (RB - 1)) << 17) | (uint32_t)c4.z;
    int p3 = atomicAdd(&hist[r4.w >> RBSH], 1);
    sorted[p3] = ((uint32_t)(r4.w & (RB - 1)) << 17) | (uint32_t)c4.w;
  }
  __syncthreads();
  int wv = tid >> 6, lane = tid & 63;
  for (int b = wv; b < NB; b += 16) {   // wave-cooperative contiguous run copy
    int st = b ? scanv[b - 1] : 0;
    int en = scanv[b];
    int gb = res[b];
    for (int j = st + lane; j < en; j += 64)
      temp[gb + (j - st)] = sorted[j];
  }
}

// ---- per-bucket CSR build (1024 thr, uint4); emits deg -> dis, offs, cnts ----
__launch_bounds__(1024)
__global__ void k_csr_build(const int* __restrict__ gcur,
                            const uint32_t* __restrict__ temp, int N,
                            int* __restrict__ offs, int* __restrict__ cnts,
                            float* __restrict__ dis, int* __restrict__ csr) {
  __shared__ int cnt[RB];   // per-node count -> cursor
  __shared__ int S[256];
  int b = blockIdx.x;
  int tid = threadIdx.x;
  int base = b * BSTRIDE;   // 16B-aligned (BSTRIDE % 4 == 0)
  int cb = gcur[b] - base;
  int cb4 = cb & ~3;

  if (tid < RB) cnt[tid] = 0;
  __syncthreads();
  for (int i = tid * 4; i < cb4; i += 4096) {
    uint4 t4 = *(const uint4*)&temp[base + i];
    atomicAdd(&cnt[t4.x >> 17], 1);
    atomicAdd(&cnt[t4.y >> 17], 1);
    atomicAdd(&cnt[t4.z >> 17], 1);
    atomicAdd(&cnt[t4.w >> 17], 1);
  }
  if (tid < cb - cb4)                     // tail 0..3
    atomicAdd(&cnt[temp[base + cb4 + tid] >> 17], 1);
  __syncthreads();
  int a0 = 0, a1 = 0, ex0 = 0;
  if (tid < 256) {
    a0 = cnt[2 * tid]; a1 = cnt[2 * tid + 1];
    S[tid] = a0 + a1;
  }
  __syncthreads();
  for (int d = 1; d < 256; d <<= 1) {
    int v = 0;
    if (tid < 256 && tid >= d) v = S[tid - d];
    __syncthreads();
    if (tid < 256) S[tid] += v;
    __syncthreads();
  }
  if (tid < 256) {
    ex0 = S[tid] - (a0 + a1);
    int r0 = b * RB + 2 * tid;
    if (r0 < N) {
      dis[r0] = rsqrtf((float)(a0 + 1));
      offs[r0] = base + ex0;
      cnts[r0] = a0;
    }
    if (r0 + 1 < N) {
      dis[r0 + 1] = rsqrtf((float)(a1 + 1));
      offs[r0 + 1] = base + ex0 + a0;
      cnts[r0 + 1] = a1;
    }
  }
  __syncthreads();
  if (tid < 256) {
    cnt[2 * tid]     = ex0;       // cursor start
    cnt[2 * tid + 1] = ex0 + a0;
  }
  __syncthreads();
  for (int i = tid * 4; i < cb4; i += 4096) {
    uint4 t4 = *(const uint4*)&temp[base + i];
    int p0 = atomicAdd(&cnt[t4.x >> 17], 1);
    csr[base + p0] = (int)(t4.x & 0x1FFFF);
    int p1 = atomicAdd(&cnt[t4.y >> 17], 1);
    csr[base + p1] = (int)(t4.y & 0x1FFFF);
    int p2 = atomicAdd(&cnt[t4.z >> 17], 1);
    csr[base + p2] = (int)(t4.z & 0x1FFFF);
    int p3 = atomicAdd(&cnt[t4.w >> 17], 1);
    csr[base + p3] = (int)(t4.w & 0x1FFFF);
  }
  if (tid < cb - cb4) {
    uint32_t pk = temp[base + cb4 + tid];
    int p = atomicAdd(&cnt[pk >> 17], 1);
    csr[base + p] = (int)(pk & 0x1FFFF);
  }
}

// ---- bf16 MFMA GEMM: h = x W + b; store hu[m*64+j] = bf16(dis[m]*h) pair ----
// Block: 512 thr = 8 waves, M-tile 128, all 128 cols -> 64 KB W-LDS amortized
// at 16 waves/CU (4/SIMD). Wave w: rows [32(w&3),+32), cols [64(w>>2),+64) as
// two 32x32 tiles. A-frags straight from global (x rows used once, v_cvt_pk);
// W in LDS bf16 [col][k], 16B-slot XOR swizzle => conflict-free b128.
// hu dword j packs feats (p, p+32), p = (j&31) | ((j&32)<<1).
__launch_bounds__(512)
__global__ void k_gemm(const float* __restrict__ x, const uint16_t* __restrict__ wbf,
                       const float* __restrict__ bias, const float* __restrict__ dis,
                       uint32_t* __restrict__ hu, int M) {
  __shared__ uint16_t wlds[32768];  // 64 KB
  int tid = threadIdx.x;
  {
    const uint4* src = (const uint4*)wbf;
#pragma unroll
    for (int i = 0; i < 8; ++i) {      // 8 * 512 = 4096 chunks = full 64 KB
      int chunk = i * 512 + tid;       // 16B chunks: col = chunk>>5, slot = chunk&31
      uint4 v = src[chunk];
      int col = chunk >> 5, s = chunk & 31;
      int sp = s ^ (col & 31);
      *(uint4*)&wlds[col * 256 + sp * 8] = v;
    }
  }
  int w = tid >> 6, l = tid & 63;
  int lr = l & 31, g = l >> 5;
  int row = blockIdx.x * 128 + (w & 3) * 32 + lr;
  int c0 = (w >> 2) * 64;
  bool valid = row < M;
  const float* xrow = x + (size_t)row * 256;
  f32x16 acc0 = {}, acc1 = {};
  __syncthreads();
#pragma unroll
  for (int kt = 0; kt < 16; ++kt) {
    int k0 = kt * 16 + g * 8;          // lane's 8 contiguous k
    float4 f0 = make_float4(0.f, 0.f, 0.f, 0.f), f1 = f0;
    if (valid) {
      f0 = *(const float4*)(xrow + k0);
      f1 = *(const float4*)(xrow + k0 + 4);
    }
    union { uint32_t u[4]; short8v v; } av;
    av.u[0] = cvt_pk(f0.x, f0.y);
    av.u[1] = cvt_pk(f0.z, f0.w);
    av.u[2] = cvt_pk(f1.x, f1.y);
    av.u[3] = cvt_pk(f1.z, f1.w);
    int sp = (kt * 2 + g) ^ lr;        // swizzled 16B slot
    short8v b0 = *(short8v*)&wlds[(c0 + lr) * 256 + sp * 8];
    short8v b1 = *(short8v*)&wlds[(c0 + 32 + lr) * 256 + sp * 8];
    acc0 = __builtin_amdgcn_mfma_f32_32x32x16_bf16(av.v, b0, acc0, 0, 0, 0);
    acc1 = __builtin_amdgcn_mfma_f32_32x32x16_bf16(av.v, b1, acc1, 0, 0, 0);
  }
  int j = lr + (w >> 2) * 32;          // hu pair index
  int p = c0 + lr;                     // actual feature col of tile0
  float bl = bias[p], bh = bias[p + 32];
#pragma unroll
  for (int r = 0; r < 16; ++r) {
    int mrow = blockIdx.x * 128 + (w & 3) * 32 + (r & 3) + 8 * (r >> 2) + 4 * g;
    if (mrow < M) {
      float di = dis[mrow];
      hu[(size_t)mrow * 64 + j] = cvt_pk(di * (acc0[r] + bl), di * (acc1[r] + bh));
    }
  }
}

// ---- aggregation: wave per node, scalar addressing, 8 gathers in flight ----
// offs/cnts readfirstlane'd -> csr reads on the scalar pipe, hu row base SGPR
// + loop-invariant lane offset. Measured at the beyond-L2 random-fetch ceiling.
__launch_bounds__(256)
__global__ void k_aggregate(const uint32_t* __restrict__ hu, const float* __restrict__ dis,
                            const int* __restrict__ offs, const int* __restrict__ cnts,
                            const int* __restrict__ csr,
                            float* __restrict__ out, int N) {
  int wid = blockIdx.x * 4 + (threadIdx.x >> 6);
  int lane = threadIdx.x & 63;
  if (wid >= N) return;
  int e0  = __builtin_amdgcn_readfirstlane(offs[wid]);
  int cnt = __builtin_amdgcn_readfirstlane(cnts[wid]);
  const int* cp = csr + e0;                       // uniform (SGPR) base
  const uint32_t* hrow = hu + ((size_t)(uint32_t)wid << 6);
  uint32_t ps = hrow[lane];
  float ax = bf_lo(ps);   // self loop: hu' already has dis folded in
  float ay = bf_hi(ps);
  int i = 0;
  for (; i + 8 <= cnt; i += 8) {                  // 8 independent gathers in flight
    int c0 = cp[i],     c1 = cp[i + 1], c2 = cp[i + 2], c3 = cp[i + 3];
    int c4 = cp[i + 4], c5 = cp[i + 5], c6 = cp[i + 6], c7 = cp[i + 7];
    uint32_t p0 = hu[((size_t)(uint32_t)c0 << 6) + lane];
    uint32_t p1 = hu[((size_t)(uint32_t)c1 << 6) + lane];
    uint32_t p2 = hu[((size_t)(uint32_t)c2 << 6) + lane];
    uint32_t p3 = hu[((size_t)(uint32_t)c3 << 6) + lane];
    uint32_t p4 = hu[((size_t)(uint32_t)c4 << 6) + lane];
    uint32_t p5 = hu[((size_t)(uint32_t)c5 << 6) + lane];
    uint32_t p6 = hu[((size_t)(uint32_t)c6 << 6) + lane];
    uint32_t p7 = hu[((size_t)(uint32_t)c7 << 6) + lane];
    ax += bf_lo(p0) + bf_lo(p1) + bf_lo(p2) + bf_lo(p3)
        + bf_lo(p4) + bf_lo(p5) + bf_lo(p6) + bf_lo(p7);
    ay += bf_hi(p0) + bf_hi(p1) + bf_hi(p2) + bf_hi(p3)
        + bf_hi(p4) + bf_hi(p5) + bf_hi(p6) + bf_hi(p7);
  }
  for (; i + 4 <= cnt; i += 4) {
    int c0 = cp[i], c1 = cp[i + 1], c2 = cp[i + 2], c3 = cp[i + 3];
    uint32_t p0 = hu[((size_t)(uint32_t)c0 << 6) + lane];
    uint32_t p1 = hu[((size_t)(uint32_t)c1 << 6) + lane];
    uint32_t p2 = hu[((size_t)(uint32_t)c2 << 6) + lane];
    uint32_t p3 = hu[((size_t)(uint32_t)c3 << 6) + lane];
    ax += bf_lo(p0) + bf_lo(p1) + bf_lo(p2) + bf_lo(p3);
    ay += bf_hi(p0) + bf_hi(p1) + bf_hi(p2) + bf_hi(p3);
  }
  for (; i < cnt; ++i) {
    int c = cp[i];
    uint32_t p = hu[((size_t)(uint32_t)c << 6) + lane];
    ax += bf_lo(p);
    ay += bf_hi(p);
  }
  float di = dis[wid];
  int p = (lane & 31) | ((lane & 32) << 1);
  float* orow = out + (size_t)wid * 128;
  __builtin_nontemporal_store(di * ax, &orow[p]);
  __builtin_nontemporal_store(di * ay, &orow[p + 32]);
}

// ---- fallback path (small workspace): count -> dis -> per-edge atomics ----
__global__ void k_count(const int* __restrict__ rows, int E, int* __restrict__ deg) {
  int e = blockIdx.x * blockDim.x + threadIdx.x;
  if (e < E) atomicAdd(&deg[rows[e]], 1);
}

__global__ void k_dis(const int* __restrict__ deg, float* __restrict__ dis, int N) {
  int i = blockIdx.x * blockDim.x + threadIdx.x;
  if (i < N) dis[i] = rsqrtf((float)(deg[i] + 1));
}

__launch_bounds__(256)
__global__ void k_selfinit(const uint32_t* __restrict__ hu, const float* __restrict__ dis,
                           float* __restrict__ out, int N) {
  int wid = blockIdx.x * 4 + (threadIdx.x >> 6);
  int lane = threadIdx.x & 63;
  if (wid >= N) return;
  float di = dis[wid];
  uint32_t p = hu[(size_t)wid * 64 + lane];
  int pc = (lane & 31) | ((lane & 32) << 1);
  out[(size_t)wid * 128 + pc] = di * bf_lo(p);
  out[(size_t)wid * 128 + pc + 32] = di * bf_hi(p);
}

__launch_bounds__(256)
__global__ void k_edge_atomic(const int* __restrict__ rows, const int* __restrict__ cols, int E,
                              const uint32_t* __restrict__ hu, const float* __restrict__ dis,
                              float* __restrict__ out) {
  int wid = blockIdx.x * 4 + (threadIdx.x >> 6);
  int lane = threadIdx.x & 63;
  if (wid >= E) return;
  int r = rows[wid], c = cols[wid];
  float w = dis[r];  // hu'[c] already carries dis[c]
  uint32_t p = hu[(size_t)c * 64 + lane];
  int pc = (lane & 31) | ((lane & 32) << 1);
  atomicAdd(&out[(size_t)r * 128 + pc], w * bf_lo(p));
  atomicAdd(&out[(size_t)r * 128 + pc + 32], w * bf_hi(p));
}

extern "C" void kernel_launch(void* const* d_in, const int* in_sizes, int n_in,
                              void* d_out, int out_size, void* d_ws, size_t ws_size,
                              hipStream_t stream) {
  const float* x    = (const float*)d_in[0];
  const int*   ei   = (const int*)d_in[1];
  const float* W    = (const float*)d_in[2];
  const float* bias = (const float*)d_in[3];
  float* out = (float*)d_out;

  const int N = in_sizes[0] / 256;   // 100000
  const int E = in_sizes[1] / 2;     // 3200000
  const int NB = (N + RB - 1) / RB;  // 196 buckets of 512 rows
  const int* rows = ei;
  const int* cols = ei + E;

  // workspace layout (256B aligned slices)
  size_t off = 0;
  auto alloc = [&](size_t bytes) -> void* {
    void* p = (char*)d_ws + off;
    off += (bytes + 255) & ~(size_t)255;
    return p;
  };
  uint32_t* hu    = (uint32_t*)alloc((size_t)N * 64 * 4);  // bf16-packed dis*h
  float*    dis   = (float*)alloc((size_t)N * 4);
  int*      deg   = (int*)alloc((size_t)N * 4);            // fallback only
  uint16_t* wbf   = (uint16_t*)alloc(32768 * 2);           // bf16 W, [col][k]
  int*      gcur  = (int*)alloc((size_t)NBMAX * 4);
  int*      offs  = (int*)alloc((size_t)N * 4);
  int*      cnts  = (int*)alloc((size_t)N * 4);
  size_t small_end = off;
  uint32_t* temp  = (uint32_t*)alloc((size_t)NB * BSTRIDE * 4);
  int*      csr   = (int*)alloc((size_t)NB * BSTRIDE * 4);
  bool full = (off <= ws_size);
  bool atomic_ok = (small_end <= ws_size);

  k_wcast<<<128, 256, 0, stream>>>(W, wbf, gcur, NB);

  if (full) {
    k_part<<<(E + CHUNK - 1) / CHUNK, 1024, 0, stream>>>(rows, cols, E, NB, gcur, temp);
    k_csr_build<<<NB, 1024, 0, stream>>>(gcur, temp, N, offs, cnts, dis, csr);
    k_gemm<<<(N + 127) / 128, 512, 0, stream>>>(x, wbf, bias, dis, hu, N);
    k_aggregate<<<(N + 3) / 4, 256, 0, stream>>>(hu, dis, offs, cnts, csr, out, N);
  } else if (atomic_ok) {
    hipMemsetAsync(deg, 0, (size_t)N * 4, stream);
    k_count<<<(E + 255) / 256, 256, 0, stream>>>(rows, E, deg);
    k_dis<<<(N + 255) / 256, 256, 0, stream>>>(deg, dis, N);
    k_gemm<<<(N + 127) / 128, 512, 0, stream>>>(x, wbf, bias, dis, hu, N);
    k_selfinit<<<(N + 3) / 4, 256, 0, stream>>>(hu, dis, out, N);
    k_edge_atomic<<<(E + 3) / 4, 256, 0, stream>>>(rows, cols, E, hu, dis, out);
  }
}